// Round 5
// baseline (194.259 us; speedup 1.0000x reference)
//
#include <hip/hip_runtime.h>

// YOLO loss, round 11: DENSE streaming — gating removed from all loads.
//
// r10 post-mortem: dense-tbox+NT won as predicted (~52-55us). New datum
// from top-5: harness fillBuffer writes 376MB at 6.8 TB/s on the same
// runs where our gated mix moves ~2.5 TB/s effective. The "2.6 TB/s cap"
// is an ACCESS-PATTERN property (HBM row-buffer locality: random 30%-mask
// gated 32-64B chunks = row activates), not a chip cap. Regime compare:
//   gated:  ~140 MB @ ~2.5 TB/s ~= 55us   (current)
//   dense:  176.6 MB @ ~6 TB/s  ~= 30us   (this kernel)
// Prior session's "all 68us" structures were scattered-AoS (2.6 TB/s
// scattered rate); dense-coalesced streaming was never tested.
//
// r11 = r9 skeleton, loads ungated:
//  - pred: 480 sequential float4/wave via global_load_lds DMA (0 VGPR)
//  - tcls: dense transposed unit-stride float4 x5 (named regs), NT
//  - tbox/mask: dense, NT. No shfl gating on loads; mask gates COMPUTE only.
//  - no block barriers; single vmcnt(0) drain.
// Predict: FETCH ~176MB, WRITE ~0.1MB, hbm_gbps >=5 TB/s, yolo_main
// 28-36us, dur ~168-175. If ~68us: read-path cap is real -> revert r10,
// ROOFLINE.

#define SS 28
#define BLOCK 256
#define WAVES (BLOCK / 64)

typedef const __attribute__((address_space(1))) void* as1cp;
typedef __attribute__((address_space(3))) void* as3p;
typedef float f32x4 __attribute__((ext_vector_type(4)));

__global__ __launch_bounds__(BLOCK) void yolo_main(
    const float4* __restrict__ pred4,   // [cells*30/4]
    const float4* __restrict__ tbox4,   // [cells]
    const float4* __restrict__ tcls4,   // [cells*5]
    const int*   __restrict__ mask,     // [cells]
    float4* __restrict__ block_part,    // [gridDim.x]
    int cells)
{
    __shared__ float  spred[WAVES][64 * 30];   // 4 x 7680 B
    __shared__ float4 sred[WAVES];

    const int tid    = threadIdx.x;
    const int lane   = tid & 63;
    const int wid    = tid >> 6;
    const int wcell0 = blockIdx.x * BLOCK + wid * 64;  // wave's first cell
    const int cell   = wcell0 + lane;

    int m = 0;
    if (cell < cells) m = __builtin_nontemporal_load(mask + cell);

    float* sp = spred[wid];
    const size_t pb4  = (size_t)wcell0 * 30 / 4;
    const size_t lim4 = (size_t)cells * 30 / 4;

    // ---- pred staging: 8 DENSE async DMA float4 loads, no VGPRs ----
    // dest = wave-uniform base + lane*16B -> float offset 4*(it*64+lane),
    // exactly linear: wave slice holds cells' records contiguously.
    #pragma unroll
    for (int it = 0; it < 8; ++it) {
        int p = it * 64 + lane;             // 0..543, valid < 480
        if (p < 480 && (pb4 + (size_t)p) < lim4) {
            __builtin_amdgcn_global_load_lds(
                (as1cp)(pred4 + pb4 + p),
                (as3p)(sp + it * 256),
                16, 0, 0);
        }
    }

    // ---- tbox: dense sequential (1KB/wave), nontemporal ----
    float4 tb = make_float4(0.f, 0.f, 0.f, 0.f);
    if (cell < cells) {
        f32x4 tv = __builtin_nontemporal_load((const f32x4*)(tbox4 + cell));
        tb.x = tv[0]; tb.y = tv[1]; tb.z = tv[2]; tb.w = tv[3];
    }

    // ---- tcls: DENSE transposed unit-stride float4, NT, 5 named slots ----
    const size_t tq0  = (size_t)wcell0 * 5;
    const size_t limt = (size_t)cells * 5;
    float4 t0v, t1v, t2v, t3v, t4v;
    int n0, n1, n2, n3, n4;
    int c0_, c1_, c2_, c3_, c4_;
    int k0_, k1_, k2_, k3_, k4_;
#define TCLS_ISSUE(I, TT, NN, CC, KK)                                   \
    {                                                                   \
        int q = (I) * 64 + lane;                                        \
        int c = q / 5;                                                  \
        int k = q - 5 * c;                                              \
        NN = __shfl(m, c, 64);                                          \
        CC = c; KK = k;                                                 \
        TT = make_float4(0.f, 0.f, 0.f, 0.f);                           \
        if (tq0 + (size_t)q < limt) {                                   \
            f32x4 tv = __builtin_nontemporal_load(                      \
                (const f32x4*)(tcls4 + tq0 + q));                       \
            TT.x = tv[0]; TT.y = tv[1]; TT.z = tv[2]; TT.w = tv[3];     \
        }                                                               \
    }
    TCLS_ISSUE(0, t0v, n0, c0_, k0_)
    TCLS_ISSUE(1, t1v, n1, c1_, k1_)
    TCLS_ISSUE(2, t2v, n2, c2_, k2_)
    TCLS_ISSUE(3, t3v, n3, c3_, k3_)
    TCLS_ISSUE(4, t4v, n4, c4_, k4_)
#undef TCLS_ISSUE

    // drain all in-flight requests (global_load_lds is vmcnt-tracked)
    asm volatile("s_waitcnt vmcnt(0)" ::: "memory");
    __builtin_amdgcn_sched_barrier(0);

    float acc_cls = 0.f, acc_noobj = 0.f, acc_reg = 0.f, acc_cont = 0.f;

    // ---- per-cell compute (pred from own LDS slice; mask gates terms) ----
    if (cell < cells) {
        const float* pr = sp + lane * 30;
        if (!m) {
            float c1 = pr[4], c2 = pr[9];
            acc_noobj = c1 * c1 + c2 * c2;          // *0.5 in finalize
        } else {
            const float invS = 1.f / 28.f;
            float txc = tb.x * invS, tyc = tb.y * invS;
            float t0 = txc - 0.5f * tb.z, t1 = tyc - 0.5f * tb.w;
            float t2 = txc + 0.5f * tb.z, t3 = tyc + 0.5f * tb.w;
            float ta = (t2 - t0) * (t3 - t1);

            float b1xc = pr[0] * invS, b1yc = pr[1] * invS;
            float a0 = b1xc - 0.5f * pr[2], a1 = b1yc - 0.5f * pr[3];
            float a2 = b1xc + 0.5f * pr[2], a3 = b1yc + 0.5f * pr[3];
            float wx = fmaxf(fminf(a2, t2) - fmaxf(a0, t0), 0.f);
            float wy = fmaxf(fminf(a3, t3) - fmaxf(a1, t1), 0.f);
            float inter = wx * wy;
            float area1 = (a2 - a0) * (a3 - a1);
            float den = area1 + ta - inter;
            float iou1 = inter / (den > 0.f ? den : 1.f);

            float b2xc = pr[5] * invS, b2yc = pr[6] * invS;
            float e0 = b2xc - 0.5f * pr[7], e1 = b2yc - 0.5f * pr[8];
            float e2 = b2xc + 0.5f * pr[7], e3 = b2yc + 0.5f * pr[8];
            wx = fmaxf(fminf(e2, t2) - fmaxf(e0, t0), 0.f);
            wy = fmaxf(fminf(e3, t3) - fmaxf(e1, t1), 0.f);
            inter = wx * wy;
            float area2 = (e2 - e0) * (e3 - e1);
            den = area2 + ta - inter;
            float iou2 = inter / (den > 0.f ? den : 1.f);

            bool take1 = iou1 > iou2;
            float best_iou = take1 ? iou1 : iou2;
            float bbx = take1 ? pr[0] : pr[5];
            float bby = take1 ? pr[1] : pr[6];
            float bbw = take1 ? pr[2] : pr[7];
            float bbh = take1 ? pr[3] : pr[8];
            float bbc = take1 ? pr[4] : pr[9];

            float dx = bbx - tb.x, dy = bby - tb.y;
            float xy = dx * dx + dy * dy;

            float dw = sqrtf(bbw) - sqrtf(tb.z);    // mask==1: where() == value
            float dh = sqrtf(bbh) - sqrtf(tb.w);
            float wh = dw * dw + dh * dh;

            acc_reg = xy + wh;

            float dc = bbc - best_iou;
            acc_cont = dc * dc;
        }
    }

    // ---- cls loss (tcls regs vs LDS pred; mask gates contribution) ----
#define TCLS_USE(TT, NN, CC, KK)                                  \
    if (NN) {                                                     \
        const float* pp = sp + CC * 30 + 10 + 4 * KK;             \
        float d0 = pp[0] - TT.x, d1 = pp[1] - TT.y;               \
        float d2 = pp[2] - TT.z, d3 = pp[3] - TT.w;               \
        acc_cls += d0 * d0 + d1 * d1 + d2 * d2 + d3 * d3;         \
    }
    TCLS_USE(t0v, n0, c0_, k0_)
    TCLS_USE(t1v, n1, c1_, k1_)
    TCLS_USE(t2v, n2, c2_, k2_)
    TCLS_USE(t3v, n3, c3_, k3_)
    TCLS_USE(t4v, n4, c4_, k4_)
#undef TCLS_USE

    // ---- wave + block reduction ----
    float4 vr = make_float4(acc_cls, acc_noobj, acc_reg, acc_cont);
    #pragma unroll
    for (int off = 32; off >= 1; off >>= 1) {
        vr.x += __shfl_down(vr.x, off, 64);
        vr.y += __shfl_down(vr.y, off, 64);
        vr.z += __shfl_down(vr.z, off, 64);
        vr.w += __shfl_down(vr.w, off, 64);
    }
    if (lane == 0) sred[wid] = vr;
    __syncthreads();
    if (tid == 0) {
        float4 r = sred[0];
        #pragma unroll
        for (int w = 1; w < WAVES; ++w) {
            r.x += sred[w].x; r.y += sred[w].y; r.z += sred[w].z; r.w += sred[w].w;
        }
        block_part[blockIdx.x] = r;
    }
}

__global__ __launch_bounds__(BLOCK) void yolo_final(
    const float4* __restrict__ part, int nparts, float* __restrict__ out, float invN)
{
    float4 v = make_float4(0.f, 0.f, 0.f, 0.f);
    for (int i = threadIdx.x; i < nparts; i += BLOCK) {
        float4 p = part[i];
        v.x += p.x; v.y += p.y; v.z += p.z; v.w += p.w;
    }
    #pragma unroll
    for (int off = 32; off >= 1; off >>= 1) {
        v.x += __shfl_down(v.x, off, 64);
        v.y += __shfl_down(v.y, off, 64);
        v.z += __shfl_down(v.z, off, 64);
        v.w += __shfl_down(v.w, off, 64);
    }
    __shared__ float4 sred[BLOCK / 64];
    int lane = threadIdx.x & 63;
    int wave = threadIdx.x >> 6;
    if (lane == 0) sred[wave] = v;
    __syncthreads();
    if (threadIdx.x == 0) {
        float4 r = sred[0];
        #pragma unroll
        for (int w = 1; w < BLOCK / 64; ++w) {
            r.x += sred[w].x; r.y += sred[w].y; r.z += sred[w].z; r.w += sred[w].w;
        }
        float cls    = r.x;
        float no_obj = 0.5f * r.y;   // L_NOOBJ
        float reg    = 5.0f * r.z;   // L_COORD
        float cont   = r.w;
        float total  = cls + no_obj + cont + reg;
        out[0] = total  * invN;
        out[1] = reg    * invN;
        out[2] = cont   * invN;
        out[3] = no_obj * invN;
        out[4] = cls    * invN;
    }
}

extern "C" void kernel_launch(void* const* d_in, const int* in_sizes, int n_in,
                              void* d_out, int out_size, void* d_ws, size_t ws_size,
                              hipStream_t stream) {
    const float* pred = (const float*)d_in[0];
    const float* tbox = (const float*)d_in[1];
    const float* tcls = (const float*)d_in[2];
    const int*   mask = (const int*)d_in[3];
    float* out = (float*)d_out;

    int cells = in_sizes[0] / 30;                 // N*S*S = 802816
    int n_img = cells / (SS * SS);                // N
    int nblocks = (cells + BLOCK - 1) / BLOCK;    // 3136

    float4* part = (float4*)d_ws;                 // nblocks * 16 bytes

    yolo_main<<<nblocks, BLOCK, 0, stream>>>(
        (const float4*)pred, (const float4*)tbox, (const float4*)tcls,
        mask, part, cells);
    yolo_final<<<1, BLOCK, 0, stream>>>(part, nblocks, out, 1.0f / (float)n_img);
}